// Round 8
// baseline (838.393 us; speedup 1.0000x reference)
//
#include <hip/hip_runtime.h>

// RationalQuadratic: 4-layer MLP conditioner (bf16 MFMA GEMMs) + RQ spline.
// R16: mids get a true depth-2 pipeline: 3 x BK=32 LDS buffers, counted
// vmcnt, ONE barrier per stage. Evidence: R15's swizzle cut FETCH 3.3x with
// zero time change -> GEMMs are not memory-bound; they sit at the m97
// 2-barrier ceiling (mids ~37% matrix, fused 50%). R13 failed from
// lookahead-1 (drain in same step), R14 from 4 sync-points + sched pinning.
// This is the catalog's T3/T4 minimum done right: per iter {WAITVM(3) [tile
// t landed, t+1 in flight; valid block-wide because s_barrier follows] ->
// s_barrier -> STAGE t+2 into the buffer whose readers finished pre-barrier
// -> ds_read/MFMA compiler-scheduled}. No vmcnt(0) in steady state, no
// sched_barrier. Mid LDS 48->72KB (2 blocks/CU). Staging addressing is
// byte-identical to R13/R14 (both refcheck-passed). Fused kernel kept at
// proven R15 form (163us).

typedef __bf16 bf16_t;
typedef __bf16 bf16x8 __attribute__((ext_vector_type(8)));
typedef float f32x4 __attribute__((ext_vector_type(4)));

#define GLOAD_LDS16(g, l)                                               \
  __builtin_amdgcn_global_load_lds(                                     \
      (const __attribute__((address_space(1))) void*)(g),               \
      (__attribute__((address_space(3))) void*)(l), 16, 0, 0)

#define WAITVM(N) asm volatile("s_waitcnt vmcnt(" #N ")" ::: "memory")
#define SBAR() __builtin_amdgcn_s_barrier()

// Bijective XCD-chunked swizzle (requires nwg % 8 == 0).
__device__ __forceinline__ void xcd_remap(int& bx, int& by) {
  const int gx = gridDim.x;
  const int nwg = gx * gridDim.y;
  const int id = blockIdx.y * gx + blockIdx.x;
  const int nid = (id & 7) * (nwg >> 3) + (id >> 3);
  bx = nid % gx;
  by = nid / gx;
}

// ---------------------------------------------------------------------------
// W (K,N) fp32 row-major -> Wt (Npad,K) bf16 row-major. grid (K/64, Npad/64).
__global__ __launch_bounds__(256) void transpose_w(
    const float* __restrict__ W, bf16_t* __restrict__ Wt,
    int K, int N, int Npad) {
  __shared__ float tile[64][65];
  const int kt = blockIdx.x * 64;
  const int nt = blockIdx.y * 64;
  const int r4 = threadIdx.x >> 6;
  const int c = threadIdx.x & 63;
#pragma unroll
  for (int i = 0; i < 16; i++) {
    int r = i * 4 + r4;
    int gn = nt + c;
    tile[r][c] = (gn < N) ? W[(size_t)(kt + r) * N + gn] : 0.0f;
  }
  __syncthreads();
#pragma unroll
  for (int i = 0; i < 16; i++) {
    int r = i * 4 + r4;
    Wt[(size_t)(nt + r) * K + kt + c] = (bf16_t)tile[c][r];
  }
}

// W3 (1024,1472) -> Wt3p (1536,1024) bf16, cols regrouped per-dim with pad:
// padded col n' = d*24 + p (p<23 real, p==23 zero). grid (16, 24).
__global__ __launch_bounds__(256) void transpose_w3p(
    const float* __restrict__ W3, bf16_t* __restrict__ Wt) {
  __shared__ float tile[64][65];
  const int kt = blockIdx.x * 64;
  const int nt = blockIdx.y * 64;
  const int r4 = threadIdx.x >> 6;
  const int c = threadIdx.x & 63;
  const int np = nt + c;
  const int d = np / 24, p = np % 24;
#pragma unroll
  for (int i = 0; i < 16; i++) {
    int r = i * 4 + r4;
    tile[r][c] = (p < 23) ? W3[(size_t)(kt + r) * 1472 + d * 23 + p] : 0.0f;
  }
  __syncthreads();
#pragma unroll
  for (int i = 0; i < 16; i++) {
    int r = i * 4 + r4;
    Wt[(size_t)(nt + r) * 1024 + kt + c] = (bf16_t)tile[c][r];
  }
}

// b3 -> 24-stride padded copy. grid (6,256).
__global__ __launch_bounds__(256) void prep_b3(const float* __restrict__ b3,
                                               float* __restrict__ b3p) {
  int t = blockIdx.x * 256 + threadIdx.x;
  if (t < 1536) {
    int d = t / 24, p = t % 24;
    b3p[t] = (p < 23) ? b3[d * 23 + p] : 0.0f;
  }
}

// ---------------------------------------------------------------------------
// Also zeroes ld_out for this chunk (fused gemm accumulates into it).
__global__ __launch_bounds__(256) void build_x(
    const float* __restrict__ x1, const float* __restrict__ mask1,
    const float* __restrict__ ctx, bf16_t* __restrict__ X,
    float* __restrict__ ld_out, int boff) {
  int idx = blockIdx.x * 256 + threadIdx.x;
  int bl = idx >> 8;
  int c = idx & 255;
  size_t b = (size_t)(boff + bl);
  float v;
  if (c < 64)       v = x1[b * 64 + c];
  else if (c < 128) v = mask1[b * 64 + (c - 64)];
  else              v = ctx[b * 128 + (c - 128)];
  X[(size_t)bl * 256 + c] = (bf16_t)v;
  if (c == 0) ld_out[b] = 0.0f;
}

// ---------------------------------------------------------------------------
// Mid GEMM: 128x256 tile, 8 waves (512 thr) in 2x4, each wave 64x64 (4x4
// frags of 16x16x32 MFMA). R16: 3-buffer BK=32 pipeline, lookahead 2,
// counted vmcnt, one barrier per stage. Bank-swizzled LDS (R7); addressing
// hoisted (R11); XCD-chunked remap (R15). ReLU epilogue.
__global__ __launch_bounds__(512, 4) void gemm_bt(
    const bf16_t* __restrict__ A, const bf16_t* __restrict__ Bt,
    const float* __restrict__ bias, bf16_t* __restrict__ Cout, int N, int K) {
  __shared__ __align__(16) bf16_t As[3][128 * 32];   // 24 KB
  __shared__ __align__(16) bf16_t Bs[3][256 * 32];   // 48 KB -> 72 KB total
  const int tid = threadIdx.x;
  const int w = tid >> 6;          // 0..7
  const int lane = tid & 63;
  int bx, by;
  xcd_remap(bx, by);
  const int m0 = by * 128;
  const int n0 = bx * 256;
  const int wm = (w & 1) * 64;
  const int wn = (w >> 1) * 64;    // 0..192
  const int lrow = lane & 15;
  const int quad = lane >> 4;

  // Staging per BK=32 tile: A = 8 x 1KB chunks (wave w -> chunk w),
  // B = 16 chunks (wave w -> chunks w, w+8). 3 loads/wave/stage (uniform).
  const bf16_t* gA;
  {
    const int byteoff = (w << 10) + lane * 16;
    const int row = byteoff >> 6;
    const int qs = ((byteoff >> 4) & 3) ^ ((row >> 1) & 3);
    gA = A + (size_t)(m0 + row) * K + qs * 8;
  }
  const bf16_t* gB0;
  const bf16_t* gB1;
  {
    int byteoff = (w << 10) + lane * 16;
    int row = byteoff >> 6;
    int qs = ((byteoff >> 4) & 3) ^ ((row >> 1) & 3);
    gB0 = Bt + (size_t)(n0 + row) * K + qs * 8;
    byteoff = ((w + 8) << 10) + lane * 16;
    row = byteoff >> 6;
    qs = ((byteoff >> 4) & 3) ^ ((row >> 1) & 3);
    gB1 = Bt + (size_t)(n0 + row) * K + qs * 8;
  }

  // Hoisted fragment LDS element-offsets (buffer-local).
  int offA[4], offB[4];
#pragma unroll
  for (int i = 0; i < 4; i++) {
    const int rowA = wm + i * 16 + lrow;
    offA[i] = rowA * 32 + (quad ^ ((rowA >> 1) & 3)) * 8;
    const int rowB = wn + i * 16 + lrow;
    offB[i] = rowB * 32 + (quad ^ ((rowB >> 1) & 3)) * 8;
  }

  f32x4 acc[4][4];
#pragma unroll
  for (int i = 0; i < 4; i++)
#pragma unroll
    for (int j = 0; j < 4; j++) acc[i][j] = (f32x4){0.f, 0.f, 0.f, 0.f};

#define MID_STAGE(BUF)                                                  \
  do {                                                                  \
    GLOAD_LDS16(gA, &As[BUF][0] + w * 512);                             \
    GLOAD_LDS16(gB0, &Bs[BUF][0] + w * 512);                            \
    GLOAD_LDS16(gB1, &Bs[BUF][0] + (w + 8) * 512);                      \
    gA += 32; gB0 += 32; gB1 += 32;                                     \
  } while (0)

  const int nt = K >> 5;  // BK=32 tiles (mids: 32, gemm0: 8)
  MID_STAGE(0);           // tile 0 -> buf0
  MID_STAGE(1);           // tile 1 -> buf1   (lookahead 2)
  int cur = 0;            // t % 3
  int stg = 2;            // (t+2) % 3
  for (int t = 0; t < nt; t++) {
    // Own tile-t loads done (t+1 stays in flight); barrier makes it
    // block-wide (every wave waited before the barrier).
    if (t + 1 < nt) WAITVM(3); else WAITVM(0);
    SBAR();
    // buf[stg]'s last readers finished at t-1, pre-barrier -> WAR safe.
    if (t + 2 < nt) MID_STAGE(stg);
    bf16x8 af[4], bfr[4];
#pragma unroll
    for (int i = 0; i < 4; i++)
      af[i] = *(const bf16x8*)(&As[cur][0] + offA[i]);
#pragma unroll
    for (int j = 0; j < 4; j++)
      bfr[j] = *(const bf16x8*)(&Bs[cur][0] + offB[j]);
#pragma unroll
    for (int i = 0; i < 4; i++)
#pragma unroll
      for (int j = 0; j < 4; j++)
        acc[i][j] = __builtin_amdgcn_mfma_f32_16x16x32_bf16(
            af[i], bfr[j], acc[i][j], 0, 0, 0);
    cur = (cur == 2) ? 0 : cur + 1;
    stg = (stg == 2) ? 0 : stg + 1;
  }
#undef MID_STAGE

  // C/D layout (m89/m91): col = lane&15, row = quad*4 + reg.
  float bv[4];
#pragma unroll
  for (int j = 0; j < 4; j++) bv[j] = bias[n0 + wn + j * 16 + lrow];
#pragma unroll
  for (int i = 0; i < 4; i++) {
    int rbase = m0 + wm + i * 16 + quad * 4;
#pragma unroll
    for (int j = 0; j < 4; j++) {
      int col = n0 + wn + j * 16 + lrow;
#pragma unroll
      for (int r = 0; r < 4; r++) {
        float v = fmaxf(acc[i][j][r] + bv[j], 0.0f);
        Cout[(size_t)(rbase + r) * N + col] = (bf16_t)v;
      }
    }
  }
}

// ---------------------------------------------------------------------------
// Fused last GEMM + RQ spline (R15 form, unchanged — proven 163us).
// Tile 128x192 (= 8 dims x 24 padded params), 8 waves 2x4, wave 64x48.
// bf16 Pt union (stride 200). XCD-chunked remap.
__global__ __launch_bounds__(512, 4) void gemm_rq_fused(
    const bf16_t* __restrict__ A, const bf16_t* __restrict__ Bt,
    const float* __restrict__ b3p, const float* __restrict__ x2,
    float* __restrict__ z_out, float* __restrict__ ld_out,
    int boff, int K) {
  union alignas(16) SM {
    struct { bf16_t As[2][128 * 32]; bf16_t Bs[2][192 * 32]; } s;  // 40960 B
    bf16_t Pt[128 * 200];                                          // 51200 B
  };
  __shared__ SM sm;
  const int tid = threadIdx.x;
  const int w = tid >> 6;          // 0..7
  const int lane = tid & 63;
  int bx, by;
  xcd_remap(bx, by);
  const int m0 = by * 128;
  const int n0 = bx * 192;
  const int wm = (w & 1) * 64;
  const int wn = (w >> 1) * 48;    // 0..144
  const int lrow = lane & 15;
  const int quad = lane >> 4;

  bf16_t* const smB = &sm.s.As[0][0];
  // Layout (elems): As[0]@0, As[1]@4096, Bs[0]@8192, Bs[1]@14336.

  // Staging: A 8 chunks/half -> wave w takes chunk w.
  //          B 12 chunks/half -> wave w takes chunk w; w<4 also chunk w+8.
  const bf16_t* gA;
  {
    const int byteoff = (w << 10) + lane * 16;
    const int row = byteoff >> 6;
    const int qs = ((byteoff >> 4) & 3) ^ ((row >> 1) & 3);
    gA = A + (size_t)(m0 + row) * K + qs * 8;
  }
  const bf16_t* gB0;
  const bf16_t* gB1;
  {
    int byteoff = (w << 10) + lane * 16;
    int row = byteoff >> 6;
    int qs = ((byteoff >> 4) & 3) ^ ((row >> 1) & 3);
    gB0 = Bt + (size_t)(n0 + row) * K + qs * 8;
    const int c1 = (w & 3) + 8;              // only used when w < 4
    byteoff = (c1 << 10) + lane * 16;
    row = byteoff >> 6;
    qs = ((byteoff >> 4) & 3) ^ ((row >> 1) & 3);
    gB1 = Bt + (size_t)(n0 + row) * K + qs * 8;
  }
  bf16_t* const dA0 = smB + w * 512;                    // h=1 at +4096
  bf16_t* const dB0 = smB + 8192 + w * 512;             // h=1 at +6144
  bf16_t* const dB1 = smB + 8192 + ((w & 3) + 8) * 512;

  // Hoisted fragment LDS element-offsets.
  int offA[4], offB3[3];
#pragma unroll
  for (int i = 0; i < 4; i++) {
    const int rowA = wm + i * 16 + lrow;
    offA[i] = rowA * 32 + (quad ^ ((rowA >> 1) & 3)) * 8;
  }
#pragma unroll
  for (int j = 0; j < 3; j++) {
    const int rowB = wn + j * 16 + lrow;
    offB3[j] = rowB * 32 + (quad ^ ((rowB >> 1) & 3)) * 8;
  }

  f32x4 acc[4][3];
#pragma unroll
  for (int i = 0; i < 4; i++)
#pragma unroll
    for (int j = 0; j < 3; j++) acc[i][j] = (f32x4){0.f, 0.f, 0.f, 0.f};

  const int nPair = K >> 6;
  for (int kp = 0; kp < nPair; kp++) {
    GLOAD_LDS16(gA, dA0);
    GLOAD_LDS16(gA + 32, dA0 + 4096);
    GLOAD_LDS16(gB0, dB0);
    GLOAD_LDS16(gB0 + 32, dB0 + 6144);
    if (w < 4) {  // wave-uniform
      GLOAD_LDS16(gB1, dB1);
      GLOAD_LDS16(gB1 + 32, dB1 + 6144);
      gB1 += 64;
    }
    gA += 64;
    gB0 += 64;
    __syncthreads();
#pragma unroll
    for (int h = 0; h < 2; h++) {
      bf16x8 af[4], bfr[3];
#pragma unroll
      for (int i = 0; i < 4; i++)
        af[i] = *(const bf16x8*)(smB + h * 4096 + offA[i]);
#pragma unroll
      for (int j = 0; j < 3; j++)
        bfr[j] = *(const bf16x8*)(smB + 8192 + h * 6144 + offB3[j]);
#pragma unroll
      for (int i = 0; i < 4; i++)
#pragma unroll
        for (int j = 0; j < 3; j++)
          acc[i][j] = __builtin_amdgcn_mfma_f32_16x16x32_bf16(
              af[i], bfr[j], acc[i][j], 0, 0, 0);
    }
    __syncthreads();
  }

  // --- P-tile (bf16, +bias) into LDS. Last barrier above guarantees no
  // wave still reads As/Bs. C/D layout: col = lane&15, row = quad*4 + reg.
  float bv[3];
#pragma unroll
  for (int j = 0; j < 3; j++) bv[j] = b3p[n0 + wn + j * 16 + lrow];
#pragma unroll
  for (int i = 0; i < 4; i++) {
    const int rbase = wm + i * 16 + quad * 4;
#pragma unroll
    for (int j = 0; j < 3; j++) {
      const int col = wn + j * 16 + lrow;
#pragma unroll
      for (int r = 0; r < 4; r++)
        sm.Pt[(rbase + r) * 200 + col] = (bf16_t)(acc[i][j][r] + bv[j]);
    }
  }
  __syncthreads();

  // --- spline: thread t handles rows (t>>3) and (t>>3)+64, dim t&7.
  const float SHIFT = 0.54132485f;     // log(e-1)
  const float SHIFT_DX = 5.1944682f;   // log(exp(6.0-0.8)-1)
  const float left = -3.0f;
  const float delta_x = 0.8f + log1pf(expf(SHIFT_DX));
  const float right = left + delta_x;
  const float scale = delta_x;
  const int dloc = tid & 7;
  const int dg = bx * 8 + dloc;

#pragma unroll
  for (int rr = 0; rr < 2; rr++) {
    const int row = (tid >> 3) + rr * 64;
    const bf16_t* pr = sm.Pt + row * 200 + dloc * 24;
    const size_t bg = (size_t)(boff + m0 + row);
    const float x = x2[bg * 64 + dg];

    // 3x ds_read_b128 (16B-aligned), then statically-indexed registers.
    bf16x8 v0 = *(const bf16x8*)(pr);
    bf16x8 v1 = *(const bf16x8*)(pr + 8);
    bf16x8 v2 = *(const bf16x8*)(pr + 16);
    float pv[24];
#pragma unroll
    for (int j = 0; j < 8; j++) pv[j] = (float)v0[j];
#pragma unroll
    for (int j = 0; j < 8; j++) pv[8 + j] = (float)v1[j];
#pragma unroll
    for (int j = 0; j < 8; j++) pv[16 + j] = (float)v2[j];

    float mw = pv[0];
#pragma unroll
    for (int j = 1; j < 8; j++) mw = fmaxf(mw, pv[j]);
    float ew[8], swv = 0.f;
#pragma unroll
    for (int j = 0; j < 8; j++) { ew[j] = expf(pv[j] - mw); swv += ew[j]; }
    float invw = 1.0f / swv;
    float cw[9];
    cw[0] = left;
    float cum = 0.f;
#pragma unroll
    for (int j = 0; j < 8; j++) {
      cum += 0.1f + 0.2f * ew[j] * invw;
      cw[j + 1] = left + scale * cum;
    }
    float mh = pv[8];
#pragma unroll
    for (int j = 9; j < 16; j++) mh = fmaxf(mh, pv[j]);
    float eh[8], shv = 0.f;
#pragma unroll
    for (int j = 0; j < 8; j++) { eh[j] = expf(pv[8 + j] - mh); shv += eh[j]; }
    float invh = 1.0f / shv;
    float chh[9];
    chh[0] = left;
    float cumh = 0.f;
#pragma unroll
    for (int j = 0; j < 8; j++) {
      cumh += 0.1f + 0.2f * eh[j] * invh;
      chh[j + 1] = left + scale * cumh;
    }
    float dv[9];
    dv[0] = 1.0f;
    dv[8] = 1.0f;
#pragma unroll
    for (int j = 0; j < 7; j++) {
      float v = pv[16 + j] + SHIFT;
      dv[j + 1] = 0.001f + ((v > 20.f) ? v : log1pf(expf(v)));
    }
    int cnt = 0;
#pragma unroll
    for (int j = 0; j < 8; j++) cnt += (cw[j] <= x) ? 1 : 0;
    cnt += ((cw[8] + 1e-6f) <= x) ? 1 : 0;
    int idx = cnt - 1;
    idx = idx < 0 ? 0 : (idx > 7 ? 7 : idx);
    float x_k = cw[0], x_k1 = cw[1], y_k = chh[0], y_k1 = chh[1];
    float d0v = dv[0], d1v = dv[1];
#pragma unroll
    for (int j = 1; j < 8; j++) {
      bool s = (idx == j);
      x_k = s ? cw[j] : x_k;
      x_k1 = s ? cw[j + 1] : x_k1;
      y_k = s ? chh[j] : y_k;
      y_k1 = s ? chh[j + 1] : y_k1;
      d0v = s ? dv[j] : d0v;
      d1v = s ? dv[j + 1] : d1v;
    }
    float x_kd = x_k1 - x_k;
    float y_kd = y_k1 - y_k;
    float s_k = y_kd / x_kd;
    float xi = (x - x_k) / x_kd;
    float xi1m = xi * (1.f - xi);
    float alpha_k = y_kd * (s_k * xi * xi + d0v * xi1m);
    float beta_k = s_k + (d1v + d0v - 2.f * s_k) * xi1m;
    float z_sp = y_k + alpha_k / fmaxf(beta_k, 1e-8f);
    float oxi = 1.f - xi;
    float num = s_k * s_k * (d1v * xi * xi + 2.f * s_k * xi1m + d0v * oxi * oxi);
    float ld_sp = logf(fmaxf(num, 1e-8f)) - 2.f * logf(fmaxf(beta_k, 1e-8f));

    bool inside = (left <= x) && (x < right);
    z_out[bg * 64 + dg] = inside ? z_sp : x;
    float ldv = inside ? ld_sp : 0.f;
    ldv += __shfl_xor(ldv, 1);
    ldv += __shfl_xor(ldv, 2);
    ldv += __shfl_xor(ldv, 4);
    if (dloc == 0) atomicAdd(&ld_out[bg], ldv);
  }
}

// ---------------------------------------------------------------------------
extern "C" void kernel_launch(void* const* d_in, const int* in_sizes, int n_in,
                              void* d_out, int out_size, void* d_ws,
                              size_t ws_size, hipStream_t stream) {
  const float* x1 = (const float*)d_in[0];
  const float* x2 = (const float*)d_in[1];
  const float* ctx = (const float*)d_in[2];
  const float* mask1 = (const float*)d_in[3];
  const float* W0 = (const float*)d_in[4];
  const float* b0 = (const float*)d_in[5];
  const float* W1 = (const float*)d_in[6];
  const float* b1 = (const float*)d_in[7];
  const float* W2 = (const float*)d_in[8];
  const float* b2 = (const float*)d_in[9];
  const float* W3 = (const float*)d_in[10];
  const float* b3 = (const float*)d_in[11];
  float* out = (float*)d_out;

  const int B = 65536;
  char* ws = (char*)d_ws;

  bf16_t* Wt0 = (bf16_t*)ws;                           // 1024x256  (512 KB)
  bf16_t* Wt1 = (bf16_t*)(ws + 524288);                // 1024x1024 (2 MB)
  bf16_t* Wt2 = (bf16_t*)(ws + 524288 + 2097152);      // 1024x1024 (2 MB)
  bf16_t* Wt3 = (bf16_t*)(ws + 524288 + 2 * 2097152);  // 1536x1024 (3 MB)
  float* b3p = (float*)(ws + 524288 + 2 * 2097152 + 3145728);  // 6 KB
  const size_t wend = 524288 + 2 * 2097152 + 3145728 + 8192;

  // Adaptive chunking, prefer C=1. Per-row: HA 2048 B + aliased region
  // 2048 B (X 512 / HB 2048 — lifetimes disjoint; P eliminated by fusion).
  int C = 4;
  if (wend + (size_t)B * 4096 <= ws_size) C = 1;
  else if (wend + (size_t)(B / 2) * 4096 <= ws_size) C = 2;
  const int Bc = B / C;
  bf16_t* HA = (bf16_t*)(ws + wend);
  char* R = ws + wend + (size_t)Bc * 2048;
  bf16_t* X = (bf16_t*)R;
  bf16_t* HB = (bf16_t*)R;
  float* ld_out = out + (size_t)B * 64;

  transpose_w<<<dim3(4, 16), 256, 0, stream>>>(W0, Wt0, 256, 1024, 1024);
  transpose_w<<<dim3(16, 16), 256, 0, stream>>>(W1, Wt1, 1024, 1024, 1024);
  transpose_w<<<dim3(16, 16), 256, 0, stream>>>(W2, Wt2, 1024, 1024, 1024);
  transpose_w3p<<<dim3(16, 24), 256, 0, stream>>>(W3, Wt3);
  prep_b3<<<6, 256, 0, stream>>>(b3, b3p);

  for (int c = 0; c < C; c++) {
    const int boff = c * Bc;
    build_x<<<Bc, 256, 0, stream>>>(x1, mask1, ctx, X, ld_out, boff);
    gemm_bt<<<dim3(4, Bc / 128), 512, 0, stream>>>(X, Wt0, b0, HA, 1024, 256);
    gemm_bt<<<dim3(4, Bc / 128), 512, 0, stream>>>(HA, Wt1, b1, HB, 1024, 1024);
    gemm_bt<<<dim3(4, Bc / 128), 512, 0, stream>>>(HB, Wt2, b2, HA, 1024, 1024);
    gemm_rq_fused<<<dim3(8, Bc / 128), 512, 0, stream>>>(
        HA, Wt3, b3p, x2, out, ld_out, boff, 1024);
  }
}

// Round 9
// 757.999 us; speedup vs baseline: 1.1061x; 1.1061x over previous
//
#include <hip/hip_runtime.h>

// RationalQuadratic: 4-layer MLP conditioner (bf16 MFMA GEMMs) + RQ spline.
// R17: gemm_bt rewritten as the 256x256 8-phase schedule (m201 template,
// re-derived): BK=64, 8 waves 2Mx4N (128x64/wave, acc[8][4]), LDS 128KB =
// 2dbuf x (A 32KB + B 32KB), 1 block/CU. Hazard discipline: phase p stages
// exactly the half-tile region whose reads completed before the previous
// barrier (A-halves read ph0/ph1 -> restaged ph2/ph3; B read ph0+ph2 ->
// restaged ph4/ph5; dbuf1 mirrored ph4-7 -> restaged ph6/ph7 + ph0/ph1 of
// next iter). Counted vmcnt(4) ONLY at ph0/ph4 (2 half-tiles stay in
// flight, 4-6 phase lead); one raw s_barrier per phase; setprio around
// each 16-MFMA cluster (T5 pays only in this structure, m218b). Evidence
// for the rewrite: R13/R14/R16 prefetch grafts on the 2-barrier template
// all regressed (m131-m141 confirmed); R15 proved not-memory-bound (FETCH
// -3.3x, time flat); mids sit at the ~40% 2-barrier ceiling. Fused kernel
// kept at proven R15 form.

typedef __bf16 bf16_t;
typedef __bf16 bf16x8 __attribute__((ext_vector_type(8)));
typedef float f32x4 __attribute__((ext_vector_type(4)));

#define GLOAD_LDS16(g, l)                                               \
  __builtin_amdgcn_global_load_lds(                                     \
      (const __attribute__((address_space(1))) void*)(g),               \
      (__attribute__((address_space(3))) void*)(l), 16, 0, 0)

#define WAITVM(N) asm volatile("s_waitcnt vmcnt(" #N ")" ::: "memory")
#define SBAR() __builtin_amdgcn_s_barrier()

// Bijective XCD-chunked swizzle (requires nwg % 8 == 0).
__device__ __forceinline__ void xcd_remap(int& bx, int& by) {
  const int gx = gridDim.x;
  const int nwg = gx * gridDim.y;
  const int id = blockIdx.y * gx + blockIdx.x;
  const int nid = (id & 7) * (nwg >> 3) + (id >> 3);
  bx = nid % gx;
  by = nid / gx;
}

// ---------------------------------------------------------------------------
// W (K,N) fp32 row-major -> Wt (Npad,K) bf16 row-major. grid (K/64, Npad/64).
__global__ __launch_bounds__(256) void transpose_w(
    const float* __restrict__ W, bf16_t* __restrict__ Wt,
    int K, int N, int Npad) {
  __shared__ float tile[64][65];
  const int kt = blockIdx.x * 64;
  const int nt = blockIdx.y * 64;
  const int r4 = threadIdx.x >> 6;
  const int c = threadIdx.x & 63;
#pragma unroll
  for (int i = 0; i < 16; i++) {
    int r = i * 4 + r4;
    int gn = nt + c;
    tile[r][c] = (gn < N) ? W[(size_t)(kt + r) * N + gn] : 0.0f;
  }
  __syncthreads();
#pragma unroll
  for (int i = 0; i < 16; i++) {
    int r = i * 4 + r4;
    Wt[(size_t)(nt + r) * K + kt + c] = (bf16_t)tile[c][r];
  }
}

// W3 (1024,1472) -> Wt3p (1536,1024) bf16, cols regrouped per-dim with pad:
// padded col n' = d*24 + p (p<23 real, p==23 zero). grid (16, 24).
__global__ __launch_bounds__(256) void transpose_w3p(
    const float* __restrict__ W3, bf16_t* __restrict__ Wt) {
  __shared__ float tile[64][65];
  const int kt = blockIdx.x * 64;
  const int nt = blockIdx.y * 64;
  const int r4 = threadIdx.x >> 6;
  const int c = threadIdx.x & 63;
  const int np = nt + c;
  const int d = np / 24, p = np % 24;
#pragma unroll
  for (int i = 0; i < 16; i++) {
    int r = i * 4 + r4;
    tile[r][c] = (p < 23) ? W3[(size_t)(kt + r) * 1472 + d * 23 + p] : 0.0f;
  }
  __syncthreads();
#pragma unroll
  for (int i = 0; i < 16; i++) {
    int r = i * 4 + r4;
    Wt[(size_t)(nt + r) * 1024 + kt + c] = (bf16_t)tile[c][r];
  }
}

// b3 -> 24-stride padded copy. grid (6,256).
__global__ __launch_bounds__(256) void prep_b3(const float* __restrict__ b3,
                                               float* __restrict__ b3p) {
  int t = blockIdx.x * 256 + threadIdx.x;
  if (t < 1536) {
    int d = t / 24, p = t % 24;
    b3p[t] = (p < 23) ? b3[d * 23 + p] : 0.0f;
  }
}

// ---------------------------------------------------------------------------
// Also zeroes ld_out for this chunk (fused gemm accumulates into it).
__global__ __launch_bounds__(256) void build_x(
    const float* __restrict__ x1, const float* __restrict__ mask1,
    const float* __restrict__ ctx, bf16_t* __restrict__ X,
    float* __restrict__ ld_out, int boff) {
  int idx = blockIdx.x * 256 + threadIdx.x;
  int bl = idx >> 8;
  int c = idx & 255;
  size_t b = (size_t)(boff + bl);
  float v;
  if (c < 64)       v = x1[b * 64 + c];
  else if (c < 128) v = mask1[b * 64 + (c - 64)];
  else              v = ctx[b * 128 + (c - 128)];
  X[(size_t)bl * 256 + c] = (bf16_t)v;
  if (c == 0) ld_out[b] = 0.0f;
}

// ---------------------------------------------------------------------------
// GEMM: 256x256 tile, BK=64, 8 waves 2Mx4N (wave out 128x64, acc[8][4]).
// 8-phase pipelined schedule (see header comment). LDS layout (elems):
//   A[d][rh][kh] @ d*16384 + rh*8192 + kh*4096      (d=dbuf, rh=row-half,
//   B[d][ch][kh] @ 32768 + d*16384 + ch*8192 + kh*4096    kh=k-half of 64)
// Quad-XOR bank swizzle within each [128][32] region (R7, conflict-free).
__global__ __launch_bounds__(512, 2) void gemm_bt(
    const bf16_t* __restrict__ A, const bf16_t* __restrict__ Bt,
    const float* __restrict__ bias, bf16_t* __restrict__ Cout, int N, int K) {
  __shared__ __align__(16) bf16_t sm[65536];  // 128 KB
  const int tid = threadIdx.x;
  const int lane = tid & 63;
  const int w = tid >> 6;
  int bx, by;
  xcd_remap(bx, by);
  const int m0 = by * 256;
  const int n0 = bx * 256;
  const int wmi = w >> 2;          // 0..1  M-half (128 rows)
  const int wnj = w & 3;           // 0..3  N-quarter (64 cols)
  const int lrow = lane & 15;
  const int quad = lane >> 4;

  // Staging source pointers: thread t covers bytes [t*16, t*16+16) of each
  // 8KB (128x32) kh-slice; swizzled source so linear LDS dest reads back
  // through the quad-XOR pattern (both-sides rule, m104/m231).
  const int byteoff = tid * 16;
  const int srow = byteoff >> 6;                              // 0..127
  const int sqs = ((byteoff >> 4) & 3) ^ ((srow >> 1) & 3);
  const bf16_t* gA0 = A + (size_t)(m0 + srow) * K + sqs * 8;        // A rows 0-127
  const bf16_t* gA1 = A + (size_t)(m0 + 128 + srow) * K + sqs * 8;  // A rows 128-255
  const bf16_t* gB0 = Bt + (size_t)(n0 + srow) * K + sqs * 8;       // B cols 0-127
  const bf16_t* gB1 = Bt + (size_t)(n0 + 128 + srow) * K + sqs * 8; // B cols 128-255
  const int dstT = tid * 8;  // elems; per-wave uniform base + lane*16B

#define ST_A(PTR, D, RH)                                                 \
  do {                                                                   \
    GLOAD_LDS16(PTR, sm + (D) * 16384 + (RH) * 8192 + dstT);             \
    GLOAD_LDS16(PTR + 32, sm + (D) * 16384 + (RH) * 8192 + 4096 + dstT); \
    PTR += 64;                                                           \
  } while (0)
#define ST_B(PTR, D, CH)                                                 \
  do {                                                                   \
    GLOAD_LDS16(PTR, sm + 32768 + (D) * 16384 + (CH) * 8192 + dstT);     \
    GLOAD_LDS16(PTR + 32,                                                \
                sm + 32768 + (D) * 16384 + (CH) * 8192 + 4096 + dstT);   \
    PTR += 64;                                                           \
  } while (0)

  // Fragment LDS element-offsets (within a [d][kh] region).
  int aoff[8];
#pragma unroll
  for (int mi = 0; mi < 8; mi++) {
    const int r = mi * 16 + lrow;
    aoff[mi] = wmi * 8192 + r * 32 + (quad ^ ((r >> 1) & 3)) * 8;
  }
  int boff[4];
#pragma unroll
  for (int nj = 0; nj < 4; nj++) {
    const int c = (wnj & 1) * 64 + nj * 16 + lrow;
    boff[nj] = 32768 + (wnj >> 1) * 8192 + c * 32 + (quad ^ ((c >> 1) & 3)) * 8;
  }

#define RD_AF(DST, D, MIB)                                               \
  _Pragma("unroll") for (int q = 0; q < 4; q++)                          \
    _Pragma("unroll") for (int kk = 0; kk < 2; kk++)                     \
      DST[q][kk] =                                                       \
          *(const bf16x8*)(sm + (D) * 16384 + kk * 4096 + aoff[(MIB) + q]);
#define RD_BF(DST, D, NJB)                                               \
  _Pragma("unroll") for (int q = 0; q < 2; q++)                          \
    _Pragma("unroll") for (int kk = 0; kk < 2; kk++)                     \
      DST[q][kk] =                                                       \
          *(const bf16x8*)(sm + (D) * 16384 + kk * 4096 + boff[(NJB) + q]);
#define MM(AF, BF, MIB, NJB)                                             \
  __builtin_amdgcn_s_setprio(1);                                         \
  _Pragma("unroll") for (int q = 0; q < 4; q++)                          \
    _Pragma("unroll") for (int p = 0; p < 2; p++)                        \
      _Pragma("unroll") for (int kk = 0; kk < 2; kk++)                   \
        acc[(MIB) + q][(NJB) + p] = __builtin_amdgcn_mfma_f32_16x16x32_bf16( \
            AF[q][kk], BF[p][kk], acc[(MIB) + q][(NJB) + p], 0, 0, 0);   \
  __builtin_amdgcn_s_setprio(0);

  f32x4 acc[8][4];
#pragma unroll
  for (int i = 0; i < 8; i++)
#pragma unroll
    for (int j = 0; j < 4; j++) acc[i][j] = (f32x4){0.f, 0.f, 0.f, 0.f};

  // Prologue = virtual iter -1, phases 2..7: tile0 full + tile1 A-halves.
  ST_A(gA0, 0, 0);  // t0 A-lo
  ST_A(gA1, 0, 1);  // t0 A-hi
  ST_B(gB0, 0, 0);  // t0 B-lo
  ST_B(gB1, 0, 1);  // t0 B-hi
  ST_A(gA0, 1, 0);  // t1 A-lo
  ST_A(gA1, 1, 1);  // t1 A-hi

  const int nI = K >> 7;  // two BK=64 tiles per iteration
  for (int i = 0; i < nI; i++) {
    const bool nl = (i + 1 < nI);
    bf16x8 afA[4][2], afB[4][2], bfrA[2][2], bfrB[2][2];
    // ---- ph0: consume dbuf0 (tile 2i) quadrant (mi0-3, nj0-1)
    WAITVM(4);
    SBAR();
    ST_B(gB0, 1, 0);            // tile 2i+1 B-lo (reads ended prev iter ph6)
    RD_AF(afA, 0, 0);
    RD_BF(bfrA, 0, 0);
    MM(afA, bfrA, 0, 0);
    // ---- ph1: (mi4-7, nj0-1)
    SBAR();
    ST_B(gB1, 1, 1);            // tile 2i+1 B-hi
    RD_AF(afB, 0, 4);
    MM(afB, bfrA, 4, 0);
    // ---- ph2: (mi0-3, nj2-3)   [dbuf0.A reads ended ph1 -> restage A]
    SBAR();
    if (nl) ST_A(gA0, 0, 0);    // tile 2i+2 A-lo
    RD_BF(bfrB, 0, 2);
    MM(afA, bfrB, 0, 2);
    // ---- ph3: (mi4-7, nj2-3)
    SBAR();
    if (nl) ST_A(gA1, 0, 1);    // tile 2i+2 A-hi
    MM(afB, bfrB, 4, 2);
    // ---- ph4: consume dbuf1 (tile 2i+1); dbuf0.B reads ended ph2
    if (nl) { WAITVM(4); } else { WAITVM(0); }
    SBAR();
    if (nl) ST_B(gB0, 0, 0);    // tile 2i+2 B-lo
    RD_AF(afA, 1, 0);
    RD_BF(bfrA, 1, 0);
    MM(afA, bfrA, 0, 0);
    // ---- ph5
    SBAR();
    if (nl) ST_B(gB1, 0, 1);    // tile 2i+2 B-hi
    RD_AF(afB, 1, 4);
    MM(afB, bfrA, 4, 0);
    // ---- ph6: dbuf1.A reads ended ph5
    SBAR();
    if (nl) ST_A(gA0, 1, 0);    // tile 2i+3 A-lo
    RD_BF(bfrB, 1, 2);
    MM(afA, bfrB, 0, 2);
    // ---- ph7
    SBAR();
    if (nl) ST_A(gA1, 1, 1);    // tile 2i+3 A-hi
    MM(afB, bfrB, 4, 2);
  }
#undef ST_A
#undef ST_B
#undef RD_AF
#undef RD_BF
#undef MM

  // C/D layout (m89/m91): col = lane&15, row = quad*4 + reg.
  float bv[4];
#pragma unroll
  for (int j = 0; j < 4; j++) bv[j] = bias[n0 + wnj * 64 + j * 16 + lrow];
#pragma unroll
  for (int i = 0; i < 8; i++) {
    int rbase = m0 + wmi * 128 + i * 16 + quad * 4;
#pragma unroll
    for (int j = 0; j < 4; j++) {
      int col = n0 + wnj * 64 + j * 16 + lrow;
#pragma unroll
      for (int r = 0; r < 4; r++) {
        float v = fmaxf(acc[i][j][r] + bv[j], 0.0f);
        Cout[(size_t)(rbase + r) * N + col] = (bf16_t)v;
      }
    }
  }
}

// ---------------------------------------------------------------------------
// Fused last GEMM + RQ spline (R15 form, unchanged — proven 163us).
// Tile 128x192 (= 8 dims x 24 padded params), 8 waves 2x4, wave 64x48.
// bf16 Pt union (stride 200). XCD-chunked remap.
__global__ __launch_bounds__(512, 4) void gemm_rq_fused(
    const bf16_t* __restrict__ A, const bf16_t* __restrict__ Bt,
    const float* __restrict__ b3p, const float* __restrict__ x2,
    float* __restrict__ z_out, float* __restrict__ ld_out,
    int boff, int K) {
  union alignas(16) SM {
    struct { bf16_t As[2][128 * 32]; bf16_t Bs[2][192 * 32]; } s;  // 40960 B
    bf16_t Pt[128 * 200];                                          // 51200 B
  };
  __shared__ SM sm;
  const int tid = threadIdx.x;
  const int w = tid >> 6;          // 0..7
  const int lane = tid & 63;
  int bx, by;
  xcd_remap(bx, by);
  const int m0 = by * 128;
  const int n0 = bx * 192;
  const int wm = (w & 1) * 64;
  const int wn = (w >> 1) * 48;    // 0..144
  const int lrow = lane & 15;
  const int quad = lane >> 4;

  bf16_t* const smB = &sm.s.As[0][0];
  // Layout (elems): As[0]@0, As[1]@4096, Bs[0]@8192, Bs[1]@14336.

  const bf16_t* gA;
  {
    const int byteoff = (w << 10) + lane * 16;
    const int row = byteoff >> 6;
    const int qs = ((byteoff >> 4) & 3) ^ ((row >> 1) & 3);
    gA = A + (size_t)(m0 + row) * K + qs * 8;
  }
  const bf16_t* gB0;
  const bf16_t* gB1;
  {
    int byteoff = (w << 10) + lane * 16;
    int row = byteoff >> 6;
    int qs = ((byteoff >> 4) & 3) ^ ((row >> 1) & 3);
    gB0 = Bt + (size_t)(n0 + row) * K + qs * 8;
    const int c1 = (w & 3) + 8;              // only used when w < 4
    byteoff = (c1 << 10) + lane * 16;
    row = byteoff >> 6;
    qs = ((byteoff >> 4) & 3) ^ ((row >> 1) & 3);
    gB1 = Bt + (size_t)(n0 + row) * K + qs * 8;
  }
  bf16_t* const dA0 = smB + w * 512;                    // h=1 at +4096
  bf16_t* const dB0 = smB + 8192 + w * 512;             // h=1 at +6144
  bf16_t* const dB1 = smB + 8192 + ((w & 3) + 8) * 512;

  int offA[4], offB3[3];
#pragma unroll
  for (int i = 0; i < 4; i++) {
    const int rowA = wm + i * 16 + lrow;
    offA[i] = rowA * 32 + (quad ^ ((rowA >> 1) & 3)) * 8;
  }
#pragma unroll
  for (int j = 0; j < 3; j++) {
    const int rowB = wn + j * 16 + lrow;
    offB3[j] = rowB * 32 + (quad ^ ((rowB >> 1) & 3)) * 8;
  }

  f32x4 acc[4][3];
#pragma unroll
  for (int i = 0; i < 4; i++)
#pragma unroll
    for (int j = 0; j < 3; j++) acc[i][j] = (f32x4){0.f, 0.f, 0.f, 0.f};

  const int nPair = K >> 6;
  for (int kp = 0; kp < nPair; kp++) {
    GLOAD_LDS16(gA, dA0);
    GLOAD_LDS16(gA + 32, dA0 + 4096);
    GLOAD_LDS16(gB0, dB0);
    GLOAD_LDS16(gB0 + 32, dB0 + 6144);
    if (w < 4) {  // wave-uniform
      GLOAD_LDS16(gB1, dB1);
      GLOAD_LDS16(gB1 + 32, dB1 + 6144);
      gB1 += 64;
    }
    gA += 64;
    gB0 += 64;
    __syncthreads();
#pragma unroll
    for (int h = 0; h < 2; h++) {
      bf16x8 af[4], bfr[3];
#pragma unroll
      for (int i = 0; i < 4; i++)
        af[i] = *(const bf16x8*)(smB + h * 4096 + offA[i]);
#pragma unroll
      for (int j = 0; j < 3; j++)
        bfr[j] = *(const bf16x8*)(smB + 8192 + h * 6144 + offB3[j]);
#pragma unroll
      for (int i = 0; i < 4; i++)
#pragma unroll
        for (int j = 0; j < 3; j++)
          acc[i][j] = __builtin_amdgcn_mfma_f32_16x16x32_bf16(
              af[i], bfr[j], acc[i][j], 0, 0, 0);
    }
    __syncthreads();
  }

  // --- P-tile (bf16, +bias) into LDS. C/D layout: col=lane&15, row=quad*4+r.
  float bv[3];
#pragma unroll
  for (int j = 0; j < 3; j++) bv[j] = b3p[n0 + wn + j * 16 + lrow];
#pragma unroll
  for (int i = 0; i < 4; i++) {
    const int rbase = wm + i * 16 + quad * 4;
#pragma unroll
    for (int j = 0; j < 3; j++) {
      const int col = wn + j * 16 + lrow;
#pragma unroll
      for (int r = 0; r < 4; r++)
        sm.Pt[(rbase + r) * 200 + col] = (bf16_t)(acc[i][j][r] + bv[j]);
    }
  }
  __syncthreads();

  // --- spline: thread t handles rows (t>>3) and (t>>3)+64, dim t&7.
  const float SHIFT = 0.54132485f;     // log(e-1)
  const float SHIFT_DX = 5.1944682f;   // log(exp(6.0-0.8)-1)
  const float left = -3.0f;
  const float delta_x = 0.8f + log1pf(expf(SHIFT_DX));
  const float right = left + delta_x;
  const float scale = delta_x;
  const int dloc = tid & 7;
  const int dg = bx * 8 + dloc;

#pragma unroll
  for (int rr = 0; rr < 2; rr++) {
    const int row = (tid >> 3) + rr * 64;
    const bf16_t* pr = sm.Pt + row * 200 + dloc * 24;
    const size_t bg = (size_t)(boff + m0 + row);
    const float x = x2[bg * 64 + dg];

    bf16x8 v0 = *(const bf16x8*)(pr);
    bf16x8 v1 = *(const bf16x8*)(pr + 8);
    bf16x8 v2 = *(const bf16x8*)(pr + 16);
    float pv[24];
#pragma unroll
    for (int j = 0; j < 8; j++) pv[j] = (float)v0[j];
#pragma unroll
    for (int j = 0; j < 8; j++) pv[8 + j] = (float)v1[j];
#pragma unroll
    for (int j = 0; j < 8; j++) pv[16 + j] = (float)v2[j];

    float mw = pv[0];
#pragma unroll
    for (int j = 1; j < 8; j++) mw = fmaxf(mw, pv[j]);
    float ew[8], swv = 0.f;
#pragma unroll
    for (int j = 0; j < 8; j++) { ew[j] = expf(pv[j] - mw); swv += ew[j]; }
    float invw = 1.0f / swv;
    float cw[9];
    cw[0] = left;
    float cum = 0.f;
#pragma unroll
    for (int j = 0; j < 8; j++) {
      cum += 0.1f + 0.2f * ew[j] * invw;
      cw[j + 1] = left + scale * cum;
    }
    float mh = pv[8];
#pragma unroll
    for (int j = 9; j < 16; j++) mh = fmaxf(mh, pv[j]);
    float eh[8], shv = 0.f;
#pragma unroll
    for (int j = 0; j < 8; j++) { eh[j] = expf(pv[8 + j] - mh); shv += eh[j]; }
    float invh = 1.0f / shv;
    float chh[9];
    chh[0] = left;
    float cumh = 0.f;
#pragma unroll
    for (int j = 0; j < 8; j++) {
      cumh += 0.1f + 0.2f * eh[j] * invh;
      chh[j + 1] = left + scale * cumh;
    }
    float dv[9];
    dv[0] = 1.0f;
    dv[8] = 1.0f;
#pragma unroll
    for (int j = 0; j < 7; j++) {
      float v = pv[16 + j] + SHIFT;
      dv[j + 1] = 0.001f + ((v > 20.f) ? v : log1pf(expf(v)));
    }
    int cnt = 0;
#pragma unroll
    for (int j = 0; j < 8; j++) cnt += (cw[j] <= x) ? 1 : 0;
    cnt += ((cw[8] + 1e-6f) <= x) ? 1 : 0;
    int idx = cnt - 1;
    idx = idx < 0 ? 0 : (idx > 7 ? 7 : idx);
    float x_k = cw[0], x_k1 = cw[1], y_k = chh[0], y_k1 = chh[1];
    float d0v = dv[0], d1v = dv[1];
#pragma unroll
    for (int j = 1; j < 8; j++) {
      bool s = (idx == j);
      x_k = s ? cw[j] : x_k;
      x_k1 = s ? cw[j + 1] : x_k1;
      y_k = s ? chh[j] : y_k;
      y_k1 = s ? chh[j + 1] : y_k1;
      d0v = s ? dv[j] : d0v;
      d1v = s ? dv[j + 1] : d1v;
    }
    float x_kd = x_k1 - x_k;
    float y_kd = y_k1 - y_k;
    float s_k = y_kd / x_kd;
    float xi = (x - x_k) / x_kd;
    float xi1m = xi * (1.f - xi);
    float alpha_k = y_kd * (s_k * xi * xi + d0v * xi1m);
    float beta_k = s_k + (d1v + d0v - 2.f * s_k) * xi1m;
    float z_sp = y_k + alpha_k / fmaxf(beta_k, 1e-8f);
    float oxi = 1.f - xi;
    float num = s_k * s_k * (d1v * xi * xi + 2.f * s_k * xi1m + d0v * oxi * oxi);
    float ld_sp = logf(fmaxf(num, 1e-8f)) - 2.f * logf(fmaxf(beta_k, 1e-8f));

    bool inside = (left <= x) && (x < right);
    z_out[bg * 64 + dg] = inside ? z_sp : x;
    float ldv = inside ? ld_sp : 0.f;
    ldv += __shfl_xor(ldv, 1);
    ldv += __shfl_xor(ldv, 2);
    ldv += __shfl_xor(ldv, 4);
    if (dloc == 0) atomicAdd(&ld_out[bg], ldv);
  }
}

// ---------------------------------------------------------------------------
extern "C" void kernel_launch(void* const* d_in, const int* in_sizes, int n_in,
                              void* d_out, int out_size, void* d_ws,
                              size_t ws_size, hipStream_t stream) {
  const float* x1 = (const float*)d_in[0];
  const float* x2 = (const float*)d_in[1];
  const float* ctx = (const float*)d_in[2];
  const float* mask1 = (const float*)d_in[3];
  const float* W0 = (const float*)d_in[4];
  const float* b0 = (const float*)d_in[5];
  const float* W1 = (const float*)d_in[6];
  const float* b1 = (const float*)d_in[7];
  const float* W2 = (const float*)d_in[8];
  const float* b2 = (const float*)d_in[9];
  const float* W3 = (const float*)d_in[10];
  const float* b3 = (const float*)d_in[11];
  float* out = (float*)d_out;

  const int B = 65536;
  char* ws = (char*)d_ws;

  bf16_t* Wt0 = (bf16_t*)ws;                           // 1024x256  (512 KB)
  bf16_t* Wt1 = (bf16_t*)(ws + 524288);                // 1024x1024 (2 MB)
  bf16_t* Wt2 = (bf16_t*)(ws + 524288 + 2097152);      // 1024x1024 (2 MB)
  bf16_t* Wt3 = (bf16_t*)(ws + 524288 + 2 * 2097152);  // 1536x1024 (3 MB)
  float* b3p = (float*)(ws + 524288 + 2 * 2097152 + 3145728);  // 6 KB
  const size_t wend = 524288 + 2 * 2097152 + 3145728 + 8192;

  // Adaptive chunking, prefer C=1. Per-row: HA 2048 B + aliased region
  // 2048 B (X 512 / HB 2048 — lifetimes disjoint; P eliminated by fusion).
  int C = 4;
  if (wend + (size_t)B * 4096 <= ws_size) C = 1;
  else if (wend + (size_t)(B / 2) * 4096 <= ws_size) C = 2;
  const int Bc = B / C;
  bf16_t* HA = (bf16_t*)(ws + wend);
  char* R = ws + wend + (size_t)Bc * 2048;
  bf16_t* X = (bf16_t*)R;
  bf16_t* HB = (bf16_t*)R;
  float* ld_out = out + (size_t)B * 64;

  transpose_w<<<dim3(4, 16), 256, 0, stream>>>(W0, Wt0, 256, 1024, 1024);
  transpose_w<<<dim3(16, 16), 256, 0, stream>>>(W1, Wt1, 1024, 1024, 1024);
  transpose_w<<<dim3(16, 16), 256, 0, stream>>>(W2, Wt2, 1024, 1024, 1024);
  transpose_w3p<<<dim3(16, 24), 256, 0, stream>>>(W3, Wt3);
  prep_b3<<<6, 256, 0, stream>>>(b3, b3p);

  for (int c = 0; c < C; c++) {
    const int boff = c * Bc;
    build_x<<<Bc, 256, 0, stream>>>(x1, mask1, ctx, X, ld_out, boff);
    gemm_bt<<<dim3(4, Bc / 256), 512, 0, stream>>>(X, Wt0, b0, HA, 1024, 256);
    gemm_bt<<<dim3(4, Bc / 256), 512, 0, stream>>>(HA, Wt1, b1, HB, 1024, 1024);
    gemm_bt<<<dim3(4, Bc / 256), 512, 0, stream>>>(HB, Wt2, b2, HA, 1024, 1024);
    gemm_rq_fused<<<dim3(8, Bc / 128), 512, 0, stream>>>(
        HA, Wt3, b3p, x2, out, ld_out, boff, 1024);
  }
}